// Round 1
// baseline (209.564 us; speedup 1.0000x reference)
//
#include <hip/hip_runtime.h>

#define NN 16384
#define DD 512
#define CC 256

typedef short bf16x8 __attribute__((ext_vector_type(8)));
typedef float f32x4 __attribute__((ext_vector_type(4)));

// RTNE float -> bf16 (bit pattern in a short)
__device__ inline short f2bf(float x) {
  unsigned u = __builtin_bit_cast(unsigned, x);
  unsigned r = (u + 0x7FFFu + ((u >> 16) & 1u)) >> 16;
  return (short)r;
}

__global__ void k_zero(float* __restrict__ p, int n, float* __restrict__ out) {
  int i = blockIdx.x * blockDim.x + threadIdx.x;
  if (i < n) p[i] = 0.f;
  if (i == 0) *out = 0.f;
}

// grid = 2 tensors * 256 classes * 8 chunks = 4096 blocks, 256 threads
__global__ void k_scatter(const float* __restrict__ src, const float* __restrict__ trg,
                          const int* __restrict__ lab_s, const int* __restrict__ lab_t,
                          float* __restrict__ sum_s, float* __restrict__ sum_t,
                          float* __restrict__ cnt_s, float* __restrict__ cnt_t) {
  const int b = blockIdx.x;
  const int t = b >> 11;          // tensor 0/1
  const int c = (b >> 3) & 255;   // class
  const int chunk = b & 7;        // row chunk of 2048
  const float* feat = t ? trg : src;
  const int* lab = t ? lab_t : lab_s;
  float* sum = t ? sum_t : sum_s;
  float* cnt = t ? cnt_t : cnt_s;
  const int tid = threadIdx.x;
  const int lane = tid & 63;
  const int row0 = chunk * 2048;

  float a0 = 0.f, a1 = 0.f;
  int count = 0;
  for (int it = 0; it < 32; ++it) {
    const int rbase = row0 + it * 64;
    const int l = lab[rbase + lane];
    unsigned long long m = __ballot(l == c);   // identical in all 4 waves
    count += (int)__popcll(m);
    while (m) {
      const int bit = __builtin_ctzll(m);
      m &= m - 1;
      const float* rp = feat + (size_t)(rbase + bit) * DD;
      a0 += rp[tid];
      a1 += rp[tid + 256];
    }
  }
  atomicAdd(sum + c * DD + tid, a0);
  atomicAdd(sum + c * DD + tid + 256, a1);
  if (tid == 0) atomicAdd(cnt + c, (float)count);
}

// grid = 256 (class), 256 threads
__global__ void k_u(const float* __restrict__ sum_s, const float* __restrict__ sum_t,
                    const float* __restrict__ cnt_s, const float* __restrict__ cnt_t,
                    unsigned short* __restrict__ u_s, unsigned short* __restrict__ u_t,
                    unsigned short* __restrict__ u_st) {
  const int c = blockIdx.x, tid = threadIdx.x;
  const float cs = cnt_s[c], ct = cnt_t[c];
  const float rs = 1.f / cs, rt = 1.f / ct, rst = 1.f / (cs + ct);
  for (int d = tid; d < DD; d += 256) {
    const float ss = sum_s[c * DD + d], st = sum_t[c * DD + d];
    u_s[c * DD + d]  = (unsigned short)f2bf(ss * rs);
    u_t[c * DD + d]  = (unsigned short)f2bf(st * rt);
    u_st[c * DD + d] = (unsigned short)f2bf((ss + st) * rst);
  }
}

// grid = 32768/32 = 1024 blocks, 256 threads (4 waves).
// Block owns 32 rows; wave w owns cols [w*64, w*64+64) for all 3 matrices.
__global__ __launch_bounds__(256) void k_main(
    const float* __restrict__ src, const float* __restrict__ trg,
    const unsigned short* __restrict__ u0, const unsigned short* __restrict__ u1,
    const unsigned short* __restrict__ u2, float* __restrict__ out) {
  const int tid = threadIdx.x;
  const int w = tid >> 6;
  const int lane = tid & 63;
  const int lhi = lane >> 4, llo = lane & 15;
  const int row0 = blockIdx.x * 32;
  const float* feat = (row0 < NN) ? (src + (size_t)row0 * DD)
                                  : (trg + (size_t)(row0 - NN) * DD);
  const unsigned short* U[3] = {u0, u1, u2};
  const int colbase = w * 64;

  f32x4 acc[3][2][4];
#pragma unroll
  for (int m = 0; m < 3; ++m)
#pragma unroll
    for (int rt = 0; rt < 2; ++rt)
#pragma unroll
      for (int ct = 0; ct < 4; ++ct)
        acc[m][rt][ct] = (f32x4){0.f, 0.f, 0.f, 0.f};

  for (int k0 = 0; k0 < DD; k0 += 32) {
    bf16x8 afr[2];
#pragma unroll
    for (int rt = 0; rt < 2; ++rt) {
      const float* ap = feat + (size_t)(rt * 16 + llo) * DD + k0 + lhi * 8;
      const float4 f0 = *reinterpret_cast<const float4*>(ap);
      const float4 f1 = *reinterpret_cast<const float4*>(ap + 4);
      bf16x8 a;
      a[0] = f2bf(f0.x); a[1] = f2bf(f0.y); a[2] = f2bf(f0.z); a[3] = f2bf(f0.w);
      a[4] = f2bf(f1.x); a[5] = f2bf(f1.y); a[6] = f2bf(f1.z); a[7] = f2bf(f1.w);
      afr[rt] = a;
    }
#pragma unroll
    for (int m = 0; m < 3; ++m) {
#pragma unroll
      for (int ct = 0; ct < 4; ++ct) {
        const unsigned short* bp =
            U[m] + (size_t)(colbase + ct * 16 + llo) * DD + k0 + lhi * 8;
        const bf16x8 bfr = *reinterpret_cast<const bf16x8*>(bp);
#pragma unroll
        for (int rt = 0; rt < 2; ++rt)
          acc[m][rt][ct] =
              __builtin_amdgcn_mfma_f32_16x16x32_bf16(afr[rt], bfr, acc[m][rt][ct], 0, 0, 0);
      }
    }
  }

  // ---- epilogue: row logsumexp (C/D layout: col = llo, row = 4*lhi + q) ----
  __shared__ float smax[3][4][32];
  __shared__ float ssum[3][4][32];
  __shared__ float bred[4];

  float lse[3][2][4];  // per (mat, rowtile, q): first max, then max+log(sum)

#pragma unroll
  for (int m = 0; m < 3; ++m)
#pragma unroll
    for (int rt = 0; rt < 2; ++rt)
#pragma unroll
      for (int q = 0; q < 4; ++q) {
        float v = fmaxf(fmaxf(acc[m][rt][0][q], acc[m][rt][1][q]),
                        fmaxf(acc[m][rt][2][q], acc[m][rt][3][q]));
#pragma unroll
        for (int off = 1; off < 16; off <<= 1)
          v = fmaxf(v, __shfl_xor(v, off));
        if (llo == 0) smax[m][w][rt * 16 + lhi * 4 + q] = v;
      }
  __syncthreads();
#pragma unroll
  for (int m = 0; m < 3; ++m)
#pragma unroll
    for (int rt = 0; rt < 2; ++rt)
#pragma unroll
      for (int q = 0; q < 4; ++q) {
        const int r = rt * 16 + lhi * 4 + q;
        lse[m][rt][q] = fmaxf(fmaxf(smax[m][0][r], smax[m][1][r]),
                              fmaxf(smax[m][2][r], smax[m][3][r]));
      }
#pragma unroll
  for (int m = 0; m < 3; ++m)
#pragma unroll
    for (int rt = 0; rt < 2; ++rt)
#pragma unroll
      for (int q = 0; q < 4; ++q) {
        float s = 0.f;
#pragma unroll
        for (int ct = 0; ct < 4; ++ct)
          s += __expf(acc[m][rt][ct][q] - lse[m][rt][q]);
#pragma unroll
        for (int off = 1; off < 16; off <<= 1)
          s += __shfl_xor(s, off);
        if (llo == 0) ssum[m][w][rt * 16 + lhi * 4 + q] = s;
      }
  __syncthreads();
#pragma unroll
  for (int m = 0; m < 3; ++m)
#pragma unroll
    for (int rt = 0; rt < 2; ++rt)
#pragma unroll
      for (int q = 0; q < 4; ++q) {
        const int r = rt * 16 + lhi * 4 + q;
        const float S = ssum[m][0][r] + ssum[m][1][r] + ssum[m][2][r] + ssum[m][3][r];
        lse[m][rt][q] += __logf(S);
      }

  // fused symmetric-KL contribution: sum over elements of
  //   e^a(2a-b-c) + e^b(2b-a-c) + e^c(2c-a-b),  a/b/c = log-probs of the 3 mats
  float ks = 0.f;
#pragma unroll
  for (int rt = 0; rt < 2; ++rt)
#pragma unroll
    for (int ct = 0; ct < 4; ++ct)
#pragma unroll
      for (int q = 0; q < 4; ++q) {
        const float a = acc[0][rt][ct][q] - lse[0][rt][q];
        const float b = acc[1][rt][ct][q] - lse[1][rt][q];
        const float c = acc[2][rt][ct][q] - lse[2][rt][q];
        ks += __expf(a) * (2.f * a - b - c) + __expf(b) * (2.f * b - a - c) +
              __expf(c) * (2.f * c - a - b);
      }
#pragma unroll
  for (int off = 1; off < 64; off <<= 1)
    ks += __shfl_xor(ks, off);
  if (lane == 0) bred[w] = ks;
  __syncthreads();
  if (tid == 0) {
    const float s = bred[0] + bred[1] + bred[2] + bred[3];
    atomicAdd(out, s * (1.f / 50331648.f));  // 1/(6 * 2N * C)
  }
}

extern "C" void kernel_launch(void* const* d_in, const int* in_sizes, int n_in,
                              void* d_out, int out_size, void* d_ws, size_t ws_size,
                              hipStream_t stream) {
  const float* src = (const float*)d_in[0];
  const float* trg = (const float*)d_in[1];
  const int* lab_s = (const int*)d_in[2];
  const int* lab_t = (const int*)d_in[3];
  float* out = (float*)d_out;

  float* sum_s = (float*)d_ws;            // [256*512]
  float* sum_t = sum_s + CC * DD;         // [256*512]
  float* cnt_s = sum_t + CC * DD;         // [256]
  float* cnt_t = cnt_s + CC;              // [256]
  unsigned short* u_s = (unsigned short*)(cnt_t + CC);  // [256*512] bf16
  unsigned short* u_t = u_s + CC * DD;
  unsigned short* u_st = u_t + CC * DD;

  const int nz = 2 * CC * DD + 2 * CC;
  k_zero<<<(nz + 255) / 256, 256, 0, stream>>>(sum_s, nz, out);
  k_scatter<<<4096, 256, 0, stream>>>(src, trg, lab_s, lab_t, sum_s, sum_t, cnt_s, cnt_t);
  k_u<<<CC, 256, 0, stream>>>(sum_s, sum_t, cnt_s, cnt_t, u_s, u_t, u_st);
  k_main<<<1024, 256, 0, stream>>>(src, trg, u_s, u_t, u_st, out);
}

// Round 2
// 133.092 us; speedup vs baseline: 1.5746x; 1.5746x over previous
//
#include <hip/hip_runtime.h>
#include <hip/hip_bf16.h>

#define NN 16384
#define DD 512
#define CC 256

typedef short bf16x8 __attribute__((ext_vector_type(8)));
typedef float f32x4 __attribute__((ext_vector_type(4)));

__device__ __forceinline__ short f2bf(float x) {
  __hip_bfloat16 h = __float2bfloat16(x);
  return __builtin_bit_cast(short, h);
}

__global__ void k_zero(float* __restrict__ p, int n, float* __restrict__ out) {
  int i = blockIdx.x * blockDim.x + threadIdx.x;
  if (i < n) p[i] = 0.f;
  if (i == 0) *out = 0.f;
}

// grid = 2 tensors * 256 classes * 8 chunks = 4096 blocks, 256 threads
__global__ void k_scatter(const float* __restrict__ src, const float* __restrict__ trg,
                          const int* __restrict__ lab_s, const int* __restrict__ lab_t,
                          float* __restrict__ sum_s, float* __restrict__ sum_t,
                          float* __restrict__ cnt_s, float* __restrict__ cnt_t) {
  const int b = blockIdx.x;
  const int t = b >> 11;          // tensor 0/1
  const int c = (b >> 3) & 255;   // class
  const int chunk = b & 7;        // row chunk of 2048
  const float* feat = t ? trg : src;
  const int* lab = t ? lab_t : lab_s;
  float* sum = t ? sum_t : sum_s;
  float* cnt = t ? cnt_t : cnt_s;
  const int tid = threadIdx.x;
  const int lane = tid & 63;
  const int row0 = chunk * 2048;

  float a0 = 0.f, a1 = 0.f;
  int count = 0;
  for (int it = 0; it < 32; ++it) {
    const int rbase = row0 + it * 64;
    const int l = lab[rbase + lane];
    unsigned long long m = __ballot(l == c);   // identical in all 4 waves
    count += (int)__popcll(m);
    while (m) {
      const int bit = __builtin_ctzll(m);
      m &= m - 1;
      const float* rp = feat + (size_t)(rbase + bit) * DD;
      a0 += rp[tid];
      a1 += rp[tid + 256];
    }
  }
  atomicAdd(sum + c * DD + tid, a0);
  atomicAdd(sum + c * DD + tid + 256, a1);
  if (tid == 0) atomicAdd(cnt + c, (float)count);
}

// grid = 256 (class), 256 threads.
// Writes the 3 prototype matrices in PACKED MFMA B-fragment order:
// per mat (131072 u16): elem = kc*8192 + tile*512 + (lhi*16+llo)*8 + j
//   where kc=k>>5, lhi=(k>>3)&3, j=k&7, tile=c>>4, llo=c&15.
__global__ void k_u(const float* __restrict__ sum_s, const float* __restrict__ sum_t,
                    const float* __restrict__ cnt_s, const float* __restrict__ cnt_t,
                    unsigned short* __restrict__ Upk) {
  const int c = blockIdx.x, tid = threadIdx.x;
  const float cs = cnt_s[c], ct = cnt_t[c];
  const float rs = 1.f / cs, rt = 1.f / ct, rst = 1.f / (cs + ct);
  const int tile = c >> 4, llo = c & 15;
#pragma unroll
  for (int kk = 0; kk < 2; ++kk) {
    const int k = tid + kk * 256;
    const float ss = sum_s[c * DD + k], st = sum_t[c * DD + k];
    const int kc = k >> 5, lhi = (k >> 3) & 3, j = k & 7;
    const int e = kc * 8192 + tile * 512 + (lhi * 16 + llo) * 8 + j;
    Upk[0 * 131072 + e] = (unsigned short)f2bf(ss * rs);
    Upk[1 * 131072 + e] = (unsigned short)f2bf(st * rt);
    Upk[2 * 131072 + e] = (unsigned short)f2bf((ss + st) * rst);
  }
}

// grid = 32768/64 = 512 blocks, 512 threads (8 waves: wave w -> wr=w>>2, cw=w&3).
// Block owns 64 rows x all 768 cols (3 mats x 256). B double-buffered in LDS.
__global__ __launch_bounds__(512) void k_main(
    const float* __restrict__ src, const float* __restrict__ trg,
    const unsigned short* __restrict__ Upk, float* __restrict__ out) {
  __shared__ short Bs[2][24576];     // 2 x 48 KB
  __shared__ float smax[3][4][64];
  __shared__ float ssum[3][4][64];
  __shared__ float bred[8];

  const int tid = threadIdx.x;
  const int w = tid >> 6, lane = tid & 63;
  const int lhi = lane >> 4, llo = lane & 15;
  const int wr = w >> 2, cw = w & 3;
  const int row0 = blockIdx.x * 64;
  const float* feat = (row0 < NN) ? src + (size_t)row0 * DD
                                  : trg + (size_t)(row0 - NN) * DD;

  f32x4 acc[3][2][4];
#pragma unroll
  for (int m = 0; m < 3; ++m)
#pragma unroll
    for (int rt = 0; rt < 2; ++rt)
#pragma unroll
      for (int ct = 0; ct < 4; ++ct)
        acc[m][rt][ct] = (f32x4){0.f, 0.f, 0.f, 0.f};

  // stage one 48KB K-chunk: 48 units of 1KB; wave w stages units s*8+w
  auto stage = [&](int kc, int buf) {
#pragma unroll
    for (int s = 0; s < 6; ++s) {
      const int u = s * 8 + w;
      const int m = u >> 4, t = u & 15;
      const unsigned short* g =
          Upk + (size_t)m * 131072 + kc * 8192 + t * 512 + lane * 8;
      const short* l = &Bs[buf][u * 512];
      __builtin_amdgcn_global_load_lds(
          (const __attribute__((address_space(1))) unsigned int*)g,
          (__attribute__((address_space(3))) unsigned int*)l, 16, 0, 0);
    }
  };

  stage(0, 0);
  int cur = 0;
  __syncthreads();

  for (int kc = 0; kc < 16; ++kc) {
    if (kc < 15) stage(kc + 1, cur ^ 1);
    bf16x8 afr[2];
#pragma unroll
    for (int rt = 0; rt < 2; ++rt) {
      const float* ap = feat + (size_t)(wr * 32 + rt * 16 + llo) * DD + kc * 32 + lhi * 8;
      const float4 f0 = *reinterpret_cast<const float4*>(ap);
      const float4 f1 = *reinterpret_cast<const float4*>(ap + 4);
      bf16x8 a;
      a[0] = f2bf(f0.x); a[1] = f2bf(f0.y); a[2] = f2bf(f0.z); a[3] = f2bf(f0.w);
      a[4] = f2bf(f1.x); a[5] = f2bf(f1.y); a[6] = f2bf(f1.z); a[7] = f2bf(f1.w);
      afr[rt] = a;
    }
#pragma unroll
    for (int m = 0; m < 3; ++m)
#pragma unroll
      for (int ct = 0; ct < 4; ++ct) {
        const bf16x8 b = *reinterpret_cast<const bf16x8*>(
            &Bs[cur][(m * 16 + cw * 4 + ct) * 512 + lane * 8]);
#pragma unroll
        for (int rt = 0; rt < 2; ++rt)
          acc[m][rt][ct] =
              __builtin_amdgcn_mfma_f32_16x16x32_bf16(afr[rt], b, acc[m][rt][ct], 0, 0, 0);
      }
    __syncthreads();
    cur ^= 1;
  }

  // ---- epilogue: per-row logsumexp over 768 cols (C/D: col=llo, row=4*lhi+q) ----
  float lse[3][2][4];

#pragma unroll
  for (int m = 0; m < 3; ++m)
#pragma unroll
    for (int rt = 0; rt < 2; ++rt)
#pragma unroll
      for (int q = 0; q < 4; ++q) {
        float v = fmaxf(fmaxf(acc[m][rt][0][q], acc[m][rt][1][q]),
                        fmaxf(acc[m][rt][2][q], acc[m][rt][3][q]));
#pragma unroll
        for (int off = 1; off < 16; off <<= 1)
          v = fmaxf(v, __shfl_xor(v, off));
        if (llo == 0) smax[m][cw][wr * 32 + rt * 16 + lhi * 4 + q] = v;
      }
  __syncthreads();
#pragma unroll
  for (int m = 0; m < 3; ++m)
#pragma unroll
    for (int rt = 0; rt < 2; ++rt)
#pragma unroll
      for (int q = 0; q < 4; ++q) {
        const int r = wr * 32 + rt * 16 + lhi * 4 + q;
        lse[m][rt][q] = fmaxf(fmaxf(smax[m][0][r], smax[m][1][r]),
                              fmaxf(smax[m][2][r], smax[m][3][r]));
      }
#pragma unroll
  for (int m = 0; m < 3; ++m)
#pragma unroll
    for (int rt = 0; rt < 2; ++rt)
#pragma unroll
      for (int q = 0; q < 4; ++q) {
        float s = 0.f;
#pragma unroll
        for (int ct = 0; ct < 4; ++ct)
          s += __expf(acc[m][rt][ct][q] - lse[m][rt][q]);
#pragma unroll
        for (int off = 1; off < 16; off <<= 1)
          s += __shfl_xor(s, off);
        if (llo == 0) ssum[m][cw][wr * 32 + rt * 16 + lhi * 4 + q] = s;
      }
  __syncthreads();
#pragma unroll
  for (int m = 0; m < 3; ++m)
#pragma unroll
    for (int rt = 0; rt < 2; ++rt)
#pragma unroll
      for (int q = 0; q < 4; ++q) {
        const int r = wr * 32 + rt * 16 + lhi * 4 + q;
        const float S = ssum[m][0][r] + ssum[m][1][r] + ssum[m][2][r] + ssum[m][3][r];
        lse[m][rt][q] += __logf(S);
      }

  // fused symmetric-KL: sum of e^a(2a-b-c) + e^b(2b-a-c) + e^c(2c-a-b)
  float ks = 0.f;
#pragma unroll
  for (int rt = 0; rt < 2; ++rt)
#pragma unroll
    for (int ct = 0; ct < 4; ++ct)
#pragma unroll
      for (int q = 0; q < 4; ++q) {
        const float a = acc[0][rt][ct][q] - lse[0][rt][q];
        const float b = acc[1][rt][ct][q] - lse[1][rt][q];
        const float c = acc[2][rt][ct][q] - lse[2][rt][q];
        ks += __expf(a) * (2.f * a - b - c) + __expf(b) * (2.f * b - a - c) +
              __expf(c) * (2.f * c - a - b);
      }
#pragma unroll
  for (int off = 1; off < 64; off <<= 1)
    ks += __shfl_xor(ks, off);
  if (lane == 0) bred[w] = ks;
  __syncthreads();
  if (tid == 0) {
    float s = 0.f;
#pragma unroll
    for (int i = 0; i < 8; ++i) s += bred[i];
    atomicAdd(out, s * (1.f / 50331648.f));  // 1/(6 * 2N * C)
  }
}

extern "C" void kernel_launch(void* const* d_in, const int* in_sizes, int n_in,
                              void* d_out, int out_size, void* d_ws, size_t ws_size,
                              hipStream_t stream) {
  const float* src = (const float*)d_in[0];
  const float* trg = (const float*)d_in[1];
  const int* lab_s = (const int*)d_in[2];
  const int* lab_t = (const int*)d_in[3];
  float* out = (float*)d_out;

  float* sum_s = (float*)d_ws;            // [256*512]
  float* sum_t = sum_s + CC * DD;         // [256*512]
  float* cnt_s = sum_t + CC * DD;         // [256]
  float* cnt_t = cnt_s + CC;              // [256]
  unsigned short* Upk = (unsigned short*)(cnt_t + CC);  // 3 x [131072] packed bf16

  const int nz = 2 * CC * DD + 2 * CC;
  k_zero<<<(nz + 255) / 256, 256, 0, stream>>>(sum_s, nz, out);
  k_scatter<<<4096, 256, 0, stream>>>(src, trg, lab_s, lab_t, sum_s, sum_t, cnt_s, cnt_t);
  k_u<<<CC, 256, 0, stream>>>(sum_s, sum_t, cnt_s, cnt_t, Upk);
  k_main<<<512, 512, 0, stream>>>(src, trg, Upk, out);
}